// Round 2
// baseline (221.220 us; speedup 1.0000x reference)
//
#include <hip/hip_runtime.h>

// SpikingLayer: T=64 sequential steps over [B=32, F=16384] state.
//   state = (x + state) - act
//   state = max(state + 1.0f, 0.0f) - 1.0f     // EXACT replication of
//                                              // relu(state - (-1)) + (-1);
//                                              // NOT the same fp32 as max(state,-1)!
//   act   = state > 0 ? floor(state) : 0
// Memory-bound streaming: 134 MB in + 134 MB out => ~43 us floor @ 6.3 TB/s.

#define T_STEPS 64
#define NCHAINS (32 * 16384)       // B*F = 524288 independent chains
#define NCHAINS4 (NCHAINS / 4)     // float4-vectorized: 131072 threads

__device__ __forceinline__ void step1(float x, float& s, float& a) {
    s = (x + s) - a;                       // membrane update (ref op order)
    s = fmaxf(s + 1.0f, 0.0f) - 1.0f;      // relu(s - thr_low) + thr_low, bit-exact
    a = (s > 0.0f) ? floorf(s) : 0.0f;     // threshold-subtract spike count
}

__global__ __launch_bounds__(256) void spiking_kernel(
    const float4* __restrict__ in, float4* __restrict__ out) {
    const int i = blockIdx.x * blockDim.x + threadIdx.x;  // chain-group id

    float4 s = {0.f, 0.f, 0.f, 0.f};
    float4 a = {0.f, 0.f, 0.f, 0.f};

    // Software pipeline: keep 2 loads in flight (latency hiding at 8 waves/CU).
    float4 x0 = in[i];
    float4 x1 = in[NCHAINS4 + i];

    for (int t = 0; t < T_STEPS; ++t) {
        float4 x = x0;
        x0 = x1;
        // clamped prefetch index: redundant last-iteration loads are L3-hits
        int tn = t + 2 < T_STEPS ? t + 2 : T_STEPS - 1;
        x1 = in[tn * NCHAINS4 + i];

        step1(x.x, s.x, a.x);
        step1(x.y, s.y, a.y);
        step1(x.z, s.z, a.z);
        step1(x.w, s.w, a.w);

        out[t * NCHAINS4 + i] = a;
    }
}

extern "C" void kernel_launch(void* const* d_in, const int* in_sizes, int n_in,
                              void* d_out, int out_size, void* d_ws, size_t ws_size,
                              hipStream_t stream) {
    const float4* in = (const float4*)d_in[0];
    float4* out = (float4*)d_out;
    // 131072 threads / 256 = 512 blocks (2 blocks/CU, 8 waves/CU)
    spiking_kernel<<<NCHAINS4 / 256, 256, 0, stream>>>(in, out);
}